// Round 12
// baseline (488.187 us; speedup 1.0000x reference)
//
#include <hip/hip_runtime.h>
#include <hip/hip_bf16.h>
#include <math.h>

typedef __attribute__((ext_vector_type(8))) short short8;
typedef __attribute__((ext_vector_type(4))) float floatx4;

// ---------------------------------------------------------------- helpers
__device__ __forceinline__ void load_lds16(const void* g, void* l) {
  __builtin_amdgcn_global_load_lds(
      (__attribute__((address_space(1))) void*)(g),
      (__attribute__((address_space(3))) void*)(l), 16, 0, 0);
}

#define MFMA16x16x32(a, b, c) __builtin_amdgcn_mfma_f32_16x16x32_bf16((a), (b), (c), 0, 0, 0)

__device__ __forceinline__ float to_f(float x) { return x; }
__device__ __forceinline__ float to_f(__hip_bfloat16 x) { return __bfloat162float(x); }

// vectorized 8-element load/store (G13: never scalar bf16)
__device__ __forceinline__ void load8f(const float* p, float* x) {
  float4 a = *(const float4*)p, b = *(const float4*)(p + 4);
  x[0] = a.x; x[1] = a.y; x[2] = a.z; x[3] = a.w;
  x[4] = b.x; x[5] = b.y; x[6] = b.z; x[7] = b.w;
}
__device__ __forceinline__ void load8f(const __hip_bfloat16* p, float* x) {
  short8 v = *(const short8*)p;
#pragma unroll
  for (int k = 0; k < 8; ++k) {
    ushort u = (ushort)v[k];
    __hip_bfloat16 h;
    *(ushort*)&h = u;
    x[k] = __bfloat162float(h);
  }
}
__device__ __forceinline__ void store8f(float* p, const float* x) {
  *(float4*)p = make_float4(x[0], x[1], x[2], x[3]);
  *(float4*)(p + 4) = make_float4(x[4], x[5], x[6], x[7]);
}
__device__ __forceinline__ void store8f(__hip_bfloat16* p, const float* x) {
  short8 o;
#pragma unroll
  for (int k = 0; k < 8; ++k) {
    __hip_bfloat16 h = __float2bfloat16(x[k]);
    o[k] = *(ushort*)&h;
  }
  *(short8*)p = o;
}

// ---------------------------------------------------------------- fused prep (1 launch replaces 8)
__global__ __launch_bounds__(256) void prep(
    const float4* __restrict__ src4, ushort* __restrict__ srcb,
    const float* __restrict__ bq, const float* __restrict__ bk,
    const float* __restrict__ bv, float* __restrict__ bqkv,
    const float* __restrict__ Wq, const float* __restrict__ Wk,
    const float* __restrict__ Wv, const float* __restrict__ Wo,
    const float* __restrict__ W1, const float* __restrict__ W2,
    __hip_bfloat16* __restrict__ WqkvT, __hip_bfloat16* __restrict__ WoT,
    __hip_bfloat16* __restrict__ W1T, __hip_bfloat16* __restrict__ W2T) {
  __shared__ __hip_bfloat16 tile[32][33];
  const int bid = blockIdx.x;
  const int tid = threadIdx.x;
  if (bid < 12288) {  // ---- src cvt ----
    int i = bid * 256 + tid;
    float4 v = src4[i];
    ushort4 o;
    __hip_bfloat16 b0 = __float2bfloat16(v.x);
    __hip_bfloat16 b1 = __float2bfloat16(v.y);
    __hip_bfloat16 b2 = __float2bfloat16(v.z);
    __hip_bfloat16 b3 = __float2bfloat16(v.w);
    o.x = *(ushort*)&b0; o.y = *(ushort*)&b1; o.z = *(ushort*)&b2; o.w = *(ushort*)&b3;
    *(ushort4*)(srcb + 4 * i) = o;
    return;
  }
  if (bid < 12294) {  // ---- bias concat ----
    int i = (bid - 12288) * 256 + tid;
    bqkv[i] = i < 512 ? bq[i] : (i < 1024 ? bk[i - 512] : bv[i - 1024]);
    return;
  }
  // ---- weight transposes ----
  const int id = bid - 12294;
  const float* tin;
  __hip_bfloat16* tout;
  int R, C, bx, by;
  if (id < 1024) {  // four 512x512
    const int which = id >> 8, t = id & 255;
    tin = which == 0 ? Wq : which == 1 ? Wk : which == 2 ? Wv : Wo;
    tout = which == 3 ? WoT : WqkvT + which * 512 * 512;
    R = 512; C = 512; bx = (t & 15) * 32; by = (t >> 4) * 32;
  } else if (id < 2048) {  // W1 [512][2048]
    const int t = id - 1024;
    tin = W1; tout = W1T; R = 512; C = 2048;
    bx = (t & 63) * 32; by = (t >> 6) * 32;
  } else {  // W2 [2048][512]
    const int t = id - 2048;
    tin = W2; tout = W2T; R = 2048; C = 512;
    bx = (t & 15) * 32; by = (t >> 4) * 32;
  }
  const int tx = tid & 31, ty = tid >> 5;
  for (int i = ty; i < 32; i += 8)
    tile[i][tx] = __float2bfloat16(tin[(size_t)(by + i) * C + bx + tx]);
  __syncthreads();
  for (int i = ty; i < 32; i += 8) tout[(size_t)(bx + i) * R + by + tx] = tile[tx][i];
}

// ---------------------------------------------------------------- GEMM: C[M,N] = A[M,K] @ BT[N,K]^T + bias, opt GELU
// m97-class structure (r7/r9-verified: ~600 TF FFN1, conflicts=0): 128x128
// tile, BK=64, 4 waves (2M x 2N), acc[4][4] (64 AGPR), single 32 KB LDS
// buffer, 2 barriers/K-tile; overlap from 3-4 independent blocks/CU.
// LDS swizzle (counter-verified): 16-B chunk c of each 128-B row holds global
// chunk c^(row&7); stage = linear global_load_lds dest + pre-swizzled GLOBAL
// source chunk (l&7)^(l>>3); read chunk' = (quad+4*kk)^(m&7).
// Staged epilogue (r9-verified: WRITE_SIZE exactly ideal, FETCH -32%).
// r12: GELU via sigmoid identity 0.5*(1+tanh t) == sigma(2t) -- identical
// math, ~8 VALU ops/elem vs ~15 (r11 showed act=1 still VALUBusy 57%).
__global__ __launch_bounds__(256, 4) void gemm128(
    const __hip_bfloat16* __restrict__ A,
    const __hip_bfloat16* __restrict__ BT,
    const float* __restrict__ bias,
    __hip_bfloat16* __restrict__ C,
    int N, int K, int act, int tiles_x) {
  __shared__ __align__(16) short8 smv[2048];  // 32 KB
  char* smc = (char*)smv;
  const int tid = threadIdx.x;
  const int wave = tid >> 6, lane = tid & 63;
  const int quad = lane >> 4, m = lane & 15;
  const int wmi = wave >> 1, wni = wave & 1;
  // bijective XCD-chunked swizzle (grid % 8 == 0 for all call sites)
  const int nwg = gridDim.x;
  const int wg = (blockIdx.x & 7) * (nwg >> 3) + (blockIdx.x >> 3);
  const int row0 = (wg / tiles_x) * 128;
  const int col0 = (wg % tiles_x) * 128;
  const int nt = K >> 6;

  // ---- staging (pre-swizzled source chunk; linear LDS dest) ----
  const int colb = (((lane & 7) ^ (lane >> 3)) << 4);
  const int rbase = wave * 8 + (lane >> 3);
  const char* pA[4];
  const char* pB[4];
  char* dA[4];
  char* dB[4];
#pragma unroll
  for (int r = 0; r < 4; ++r) {
    pA[r] = (const char*)(A + (size_t)(row0 + rbase + r * 32) * K) + colb;
    pB[r] = (const char*)(BT + (size_t)(col0 + rbase + r * 32) * K) + colb;
    dA[r] = smc + (r * 4 + wave) * 1024;
    dB[r] = smc + 16384 + (r * 4 + wave) * 1024;
  }

  // ---- fragment read indices (16-B units; typed LDS -> ds_read_b128) ----
  const int rc0 = m * 8 + ((quad)     ^ (m & 7));
  const int rc1 = m * 8 + ((quad + 4) ^ (m & 7));
  const int aB = wmi * 512;         // A rows wmi*64..+63
  const int bB = 1024 + wni * 512;  // B cols wni*64..+63

  floatx4 acc[4][4] = {};

  for (int t = 0; t < nt; ++t) {
#pragma unroll
    for (int r = 0; r < 4; ++r) { load_lds16(pA[r], dA[r]); pA[r] += 128; }
#pragma unroll
    for (int r = 0; r < 4; ++r) { load_lds16(pB[r], dB[r]); pB[r] += 128; }
    __syncthreads();  // compiler drains vmcnt(0) here (m97 behavior)
    short8 aF[4], bF[4];
    // kk0
#pragma unroll
    for (int i = 0; i < 4; ++i) aF[i] = smv[aB + i * 128 + rc0];
#pragma unroll
    for (int j = 0; j < 4; ++j) bF[j] = smv[bB + j * 128 + rc0];
#pragma unroll
    for (int i = 0; i < 4; ++i)
#pragma unroll
      for (int j = 0; j < 4; ++j) acc[i][j] = MFMA16x16x32(aF[i], bF[j], acc[i][j]);
    // kk1
#pragma unroll
    for (int i = 0; i < 4; ++i) aF[i] = smv[aB + i * 128 + rc1];
#pragma unroll
    for (int j = 0; j < 4; ++j) bF[j] = smv[bB + j * 128 + rc1];
#pragma unroll
    for (int i = 0; i < 4; ++i)
#pragma unroll
      for (int j = 0; j < 4; ++j) acc[i][j] = MFMA16x16x32(aF[i], bF[j], acc[i][j]);
    __syncthreads();
  }

  // ---------------- epilogue: acc -> swizzled bf16 LDS tile -> coalesced stores
  {
    ushort* se = (ushort*)smv;
#pragma unroll
    for (int j = 0; j < 4; ++j) {
      const int colL = wni * 64 + j * 16 + m;
      const float bj = bias[col0 + colL];
#pragma unroll
      for (int i = 0; i < 4; ++i) {
        const int rowL = wmi * 64 + i * 16 + quad * 4;
#pragma unroll
        for (int r = 0; r < 4; ++r) {
          float v = acc[i][j][r] + bj;
          if (act == 1) {
            // GELU: 0.5v(1+tanh t) == v*sigma(2t), t=0.79788456(v+0.044715v^3)
            // exp(-2t) = exp2(m * -2.3025851), m = v*(1+0.044715 v^2)
            float u = v * v;
            float p = fmaf(0.044715f, u, 1.0f);
            float mm = v * p;
            float e2 = exp2f(mm * -2.3025851f);
            v = v * __builtin_amdgcn_rcpf(1.0f + e2);
          }
          const int rL = rowL + r;
          const int byte = rL * 256 + ((colL * 2) ^ ((rL & 15) << 4));
          __hip_bfloat16 bv = __float2bfloat16(v);
          se[byte >> 1] = *(ushort*)&bv;
        }
      }
    }
    __syncthreads();
#pragma unroll
    for (int p = 0; p < 8; ++p) {
      const int rL = p * 16 + (tid >> 4);
      const int c = tid & 15;
      const int byte = rL * 256 + ((c * 16) ^ ((rL & 15) << 4));
      *(short8*)(C + (size_t)(row0 + rL) * N + col0 + c * 8) =
          *(const short8*)(smc + byte);
    }
  }
}

// ---------------------------------------------------------------- fused attention per (b,h)
// qkv fused: row stride 1536; q at col h*64, k at 512+h*64, v at 1024+h*64.
// r11: V staging via short8 global loads; ctx staged through Ks-region LDS
// (dead after softmax barrier) -> 16-B contiguous stores.
__global__ __launch_bounds__(384) void attn_fused(
    const __hip_bfloat16* __restrict__ qkv,
    const float* __restrict__ mat,
    float* __restrict__ scores,
    __hip_bfloat16* __restrict__ ctx) {
  __shared__ __align__(16) __hip_bfloat16 Ks[96 * 72];   // [l_k][d], pad 64->72; reused for ctx staging
  __shared__ __align__(16) __hip_bfloat16 Vt[64 * 104];  // [d][l_k], pad 96->104
  __shared__ __align__(16) __hip_bfloat16 Ps[96 * 104];  // [l_q][l_k], pad 96->104
  const int bh = blockIdx.x;
  const int b = bh >> 3, h = bh & 7;
  const __hip_bfloat16* qb = qkv + (size_t)b * 96 * 1536 + h * 64;
  const __hip_bfloat16* kb = qb + 512;
  const __hip_bfloat16* vb = qb + 1024;
  const int tid = threadIdx.x;

  // stage K [96][64] -> Ks, 16B chunks
  for (int c = tid; c < 768; c += 384) {
    int row = c >> 3, c8 = (c & 7) * 8;
    *(short8*)&Ks[row * 72 + c8] = *(const short8*)(kb + (size_t)row * 1536 + c8);
  }
  // stage V transposed: vectorized global read (16B), scalar LDS scatter
  for (int c = tid; c < 768; c += 384) {
    int l = c >> 3, c8 = (c & 7) * 8;
    short8 v = *(const short8*)(vb + (size_t)l * 1536 + c8);
#pragma unroll
    for (int k = 0; k < 8; ++k) ((ushort*)Vt)[(c8 + k) * 104 + l] = (ushort)v[k];
  }
  __syncthreads();

  const int wave = tid >> 6, lane = tid & 63;
  const int quad = lane >> 4, m = lane & 15;

  // phase 1: S = Q K^T (16 rows per wave, N=96, K=64)
  short8 a0 = *(const short8*)(qb + (size_t)(wave * 16 + m) * 1536 + quad * 8);
  short8 a1 = *(const short8*)(qb + (size_t)(wave * 16 + m) * 1536 + 32 + quad * 8);
  floatx4 s[6];
  const size_t mbase = ((size_t)bh * 96 + wave * 16 + quad * 4) * 96 + m;
#pragma unroll
  for (int ct = 0; ct < 6; ++ct) {
    short8 b0 = *(const short8*)&Ks[(ct * 16 + m) * 72 + quad * 8];
    short8 b1 = *(const short8*)&Ks[(ct * 16 + m) * 72 + 32 + quad * 8];
    floatx4 accv = {};
    accv = MFMA16x16x32(a0, b0, accv);
    accv = MFMA16x16x32(a1, b1, accv);
#pragma unroll
    for (int r = 0; r < 4; ++r) {
      float sv = accv[r] * 0.125f * mat[mbase + (size_t)r * 96 + ct * 16];
      accv[r] = sv;
      scores[mbase + (size_t)r * 96 + ct * 16] = sv;
    }
    s[ct] = accv;
  }

  // softmax over each row
#pragma unroll
  for (int r = 0; r < 4; ++r) {
    float mx = s[0][r];
#pragma unroll
    for (int ct = 1; ct < 6; ++ct) mx = fmaxf(mx, s[ct][r]);
#pragma unroll
    for (int dd = 1; dd < 16; dd <<= 1) mx = fmaxf(mx, __shfl_xor(mx, dd, 64));
    float sum = 0.f;
#pragma unroll
    for (int ct = 0; ct < 6; ++ct) {
      float e = __expf(s[ct][r] - mx);
      s[ct][r] = e;
      sum += e;
    }
#pragma unroll
    for (int dd = 1; dd < 16; dd <<= 1) sum += __shfl_xor(sum, dd, 64);
    float inv = 1.0f / sum;
#pragma unroll
    for (int ct = 0; ct < 6; ++ct)
      Ps[(wave * 16 + quad * 4 + r) * 104 + ct * 16 + m] = __float2bfloat16(s[ct][r] * inv);
  }
  __syncthreads();  // after this barrier Ks is dead (phase-1 reads all done)

  // phase 2: O = P V  (K = 96, 3 k-steps of 32)
  floatx4 o[4] = {};
#pragma unroll
  for (int ks = 0; ks < 3; ++ks) {
    short8 pa = *(const short8*)&Ps[(wave * 16 + m) * 104 + ks * 32 + quad * 8];
#pragma unroll
    for (int ct = 0; ct < 4; ++ct) {
      short8 vv = *(const short8*)&Vt[(ct * 16 + m) * 104 + ks * 32 + quad * 8];
      o[ct] = MFMA16x16x32(pa, vv, o[ct]);
    }
  }
  // stage O into Ks region [96][72], then coalesced 16-B stores
#pragma unroll
  for (int ct = 0; ct < 4; ++ct)
#pragma unroll
    for (int r = 0; r < 4; ++r)
      Ks[(wave * 16 + quad * 4 + r) * 72 + ct * 16 + m] = __float2bfloat16(o[ct][r]);
  __syncthreads();
  {
    __hip_bfloat16* cb = ctx + (size_t)b * 96 * 512 + h * 64;
    for (int c = tid; c < 768; c += 384) {
      int row = c >> 3, c8 = (c & 7) * 8;
      *(short8*)(cb + (size_t)row * 512 + c8) = *(const short8*)&Ks[row * 72 + c8];
    }
  }
}

// ---------------------------------------------------------------- residual + LayerNorm
// wave-per-row (D=512 = 64 lanes x 8 elems), 4 rows/block, shuffle-only reduce.
template <typename RT, typename OT>
__global__ __launch_bounds__(256) void ln_res(
    const __hip_bfloat16* __restrict__ a, const RT* __restrict__ rsd,
    const float* __restrict__ g, const float* __restrict__ be,
    OT* __restrict__ out) {
  const int row = blockIdx.x * 4 + (threadIdx.x >> 6);
  const int lane = threadIdx.x & 63;
  const size_t base = (size_t)row * 512 + lane * 8;
  float x[8], rv[8];
  load8f(a + base, x);
  load8f(rsd + base, rv);
  float s = 0.f, s2 = 0.f;
#pragma unroll
  for (int k = 0; k < 8; ++k) {
    x[k] += rv[k];
    s += x[k];
    s2 += x[k] * x[k];
  }
#pragma unroll
  for (int d = 1; d < 64; d <<= 1) {
    s += __shfl_xor(s, d, 64);
    s2 += __shfl_xor(s2, d, 64);
  }
  const float mean = s * (1.0f / 512.0f);
  const float var = s2 * (1.0f / 512.0f) - mean * mean;
  const float rstd = rsqrtf(var + 1e-5f);
  float gv[8], bv[8], y[8];
  load8f(g + lane * 8, gv);
  load8f(be + lane * 8, bv);
#pragma unroll
  for (int k = 0; k < 8; ++k) y[k] = (x[k] - mean) * rstd * gv[k] + bv[k];
  store8f(out + base, y);
}

// ---------------------------------------------------------------- launch
extern "C" void kernel_launch(void* const* d_in, const int* in_sizes, int n_in,
                              void* d_out, int out_size, void* d_ws, size_t ws_size,
                              hipStream_t stream) {
  (void)in_sizes; (void)n_in; (void)out_size; (void)ws_size;
  typedef const float* cf;
  typedef __hip_bfloat16* bf;
  cf src = (cf)d_in[0];
  cf Wq = (cf)d_in[1];  cf bq = (cf)d_in[2];
  cf Wk = (cf)d_in[3];  cf bk = (cf)d_in[4];
  cf Wv = (cf)d_in[5];  cf bv = (cf)d_in[6];
  cf mat = (cf)d_in[7];
  cf Wo = (cf)d_in[8];  cf bo = (cf)d_in[9];
  cf g1 = (cf)d_in[10]; cf be1 = (cf)d_in[11];
  cf W1 = (cf)d_in[12]; cf b1 = (cf)d_in[13];
  cf W2 = (cf)d_in[14]; cf b2 = (cf)d_in[15];
  cf g2 = (cf)d_in[16]; cf be2 = (cf)d_in[17];

  char* ws = (char*)d_ws;
  const size_t SZ = (size_t)24576 * 512 * 2;  // 25,165,824 B
  bf qkv = (bf)(ws);                  // [24576][1536] bf16 = 3*SZ
  bf ctx = (bf)(ws + 3 * SZ);
  bf hb  = (bf)(ws);                  // FFN hidden [24576][2048] = 4*SZ; qkv+ctx dead by then
  bf srcb = (bf)(ws + 4 * SZ);        // dead after qkv-gemm
  bf tmp = (bf)(ws + 4 * SZ);         // wo out -> ln1; later ffn2 out -> ln2
  bf xb  = (bf)(ws + 5 * SZ);         // post-LN1 x
  char* wt = ws + 6 * SZ;
  bf WqkvT = (bf)(wt);                          // [1536][512] bf16
  bf WoT = (bf)(wt + 1572864);
  bf W1T = (bf)(wt + 1572864 + 524288);         // [2048][512]
  bf W2T = (bf)(wt + 1572864 + 524288 + 2097152);  // [512][2048]
  float* bqkv = (float*)(wt + 1572864 + 524288 + 2097152 + 2097152);

  float* yout = (float*)d_out;
  float* scout = (float*)d_out + 12582912;  // scores after y

  // fused prep: 12288 cvt + 6 concat + 1024 (4x512x512) + 1024 (W1) + 1024 (W2)
  prep<<<15366, 256, 0, stream>>>((const float4*)src, (ushort*)srcb,
                                  bq, bk, bv, bqkv,
                                  Wq, Wk, Wv, Wo, W1, W2,
                                  WqkvT, WoT, W1T, W2T);

  // 128x128-tile m97-style GEMMs; tiles_x = N/128, grid = (M/128)*(N/128), all %8==0
  gemm128<<<2304, 256, 0, stream>>>(srcb, WqkvT, bqkv, qkv, 1536, 512, 0, 12);

  attn_fused<<<2048, 384, 0, stream>>>(qkv, mat, scout, ctx);

  gemm128<<<768, 256, 0, stream>>>(ctx, WoT, bo, tmp, 512, 512, 0, 4);
  ln_res<float, __hip_bfloat16><<<6144, 256, 0, stream>>>(tmp, src, g1, be1, xb);
  gemm128<<<3072, 256, 0, stream>>>(xb, W1T, b1, hb, 2048, 512, 1, 16);
  gemm128<<<768, 256, 0, stream>>>(hb, W2T, b2, tmp, 512, 2048, 0, 4);
  ln_res<__hip_bfloat16, float><<<6144, 256, 0, stream>>>(tmp, xb, g2, be2, yout);
}